// Round 5
// baseline (108.224 us; speedup 1.0000x reference)
//
#include <hip/hip_runtime.h>
#include <math.h>

// (B, N, D) = (32, 128, 128)
#define BATCH 32
#define NN    128
#define AP    132     // adjf fp32 pitch (floats)
#define BP    136     // bf16 pitch (shorts); rows 272B -> 16B aligned
#define NT    1024    // 16 waves
#define EPS   6e-3f   // truncation: all future |prob| <= ||x||_F^2 < EPS once reached

typedef short  frag8 __attribute__((ext_vector_type(8)));   // 8 bf16 = 4 VGPRs
typedef float  f32x4 __attribute__((ext_vector_type(4)));   // C/D operand

__device__ __forceinline__ short bf16c(float f) {
    unsigned u = __float_as_uint(f);
    unsigned r = (u + 0x7fffu + ((u >> 16) & 1u)) >> 16;
    return (short)r;
}
__device__ __forceinline__ float bf2f(short s) {
    return __uint_as_float(((unsigned)(unsigned short)s) << 16);
}

// xnewT = relu(A @ W)^T : A row-major bf16 [128][BP], W-frags in regs.
// 16 waves: wave tile = 32 rows x 32 cols. Writes xT (transposed) + ||x||_F^2.
__device__ __forceinline__ void mm_xw(const short* __restrict__ A,
                                      short* __restrict__ xT,
                                      const frag8 wf[4][2],
                                      int wr, int wc, int l15, int quad,
                                      float* ssp) {
    const f32x4 z = {0.f, 0.f, 0.f, 0.f};
    f32x4 acc[2][2];
    #pragma unroll
    for (int tr = 0; tr < 2; ++tr) { acc[tr][0] = z; acc[tr][1] = z; }
    #pragma unroll
    for (int ks = 0; ks < 4; ++ks) {
        const int kb = ks * 32 + quad * 8;
        #pragma unroll
        for (int tr = 0; tr < 2; ++tr) {
            frag8 a = *(const frag8*)&A[(wr * 32 + tr * 16 + l15) * BP + kb];
            acc[tr][0] = __builtin_amdgcn_mfma_f32_16x16x32_bf16(a, wf[ks][0], acc[tr][0], 0, 0, 0);
            acc[tr][1] = __builtin_amdgcn_mfma_f32_16x16x32_bf16(a, wf[ks][1], acc[tr][1], 0, 0, 0);
        }
    }
    float lss = 0.0f;
    #pragma unroll
    for (int tr = 0; tr < 2; ++tr)
        #pragma unroll
        for (int c2 = 0; c2 < 2; ++c2) {
            const int e  = wc * 32 + c2 * 16 + l15;      // out-feature (C col)
            const int m0 = wr * 32 + tr * 16 + quad * 4; // node (C rows, contiguous)
            f32x4 v = acc[tr][c2];
            float r0 = v[0] > 0.f ? v[0] : 0.f;
            float r1 = v[1] > 0.f ? v[1] : 0.f;
            float r2 = v[2] > 0.f ? v[2] : 0.f;
            float r3 = v[3] > 0.f ? v[3] : 0.f;
            lss = fmaf(r0, r0, lss); lss = fmaf(r1, r1, lss);
            lss = fmaf(r2, r2, lss); lss = fmaf(r3, r3, lss);
            short4 p; p.x = bf16c(r0); p.y = bf16c(r1);
            p.z = bf16c(r2); p.w = bf16c(r3);
            *(short4*)&xT[e * BP + m0] = p;
        }
    #pragma unroll
    for (int off = 32; off >= 1; off >>= 1) lss += __shfl_down(lss, off);
    if ((l15 | (quad << 4)) == 0) atomicAdd(ssp, lss);   // lane 0 per wave
    __syncthreads();
}

__global__ __launch_bounds__(NT, 1)
void gcn_kernel(const float* __restrict__ xin,
                const float* __restrict__ W,
                float* __restrict__ out) {
    extern __shared__ char smem_raw[];
    float* adjf = (float*)smem_raw;               // [128][132] fp32 (carried, normalized in place)
    short* ybuf = (short*)(adjf + NN * AP);       // [128][136] bf16: adjn / y; aliases scratch
    short* xT   = ybuf + NN * BP;                 // [128][136] bf16: xT / staged WT
    float* dinv = (float*)(xT + NN * BP);         // [128]
    float* scratch = (float*)ybuf;                // [64][AP] fp32 prob partials
    __shared__ float sumsq;
    __shared__ float wnorm;

    const int t = threadIdx.x;
    const int b = blockIdx.x;
    const int lane = t & 63, w = t >> 6;          // 16 waves
    const int wr = w >> 2, wc = w & 3;            // wave tile: rows 32*wr, cols 32*wc
    const int l15 = lane & 15, quad = lane >> 4;

    const float* xin_b = xin + (size_t)b * NN * NN;
    float*       out_b = out + (size_t)b * NN * NN;

    if (t == 0) { sumsq = 0.0f; wnorm = 0.0f; }
    __syncthreads();

    // ---- stage: adjf=0, xin->ybuf (bf16), W->xT transposed (bf16) + wnorm
    for (int e = t; e < NN * AP; e += NT) adjf[e] = 0.0f;
    for (int v = t; v < NN * NN / 4; v += NT) {
        float4 f = ((const float4*)xin_b)[v];
        const int node = v >> 5, c = (v & 31) * 4;
        short4 p; p.x = bf16c(f.x); p.y = bf16c(f.y); p.z = bf16c(f.z); p.w = bf16c(f.w);
        *(short4*)&ybuf[node * BP + c] = p;
    }
    {
        float lw = 0.0f;
        #pragma unroll
        for (int k = 0; k < 4; ++k) {
            const int idx = k * NT + t;           // float4 index into W
            float4 f = ((const float4*)W)[idx];
            lw = fmaf(f.x, f.x, lw); lw = fmaf(f.y, f.y, lw);
            lw = fmaf(f.z, f.z, lw); lw = fmaf(f.w, f.w, lw);
            const int e0 = idx * 4;
            const int d = e0 >> 7, e = e0 & 127;  // W[d][e..e+3]
            xT[(e + 0) * BP + d] = bf16c(f.x);    // WT[e][d]
            xT[(e + 1) * BP + d] = bf16c(f.y);
            xT[(e + 2) * BP + d] = bf16c(f.z);
            xT[(e + 3) * BP + d] = bf16c(f.w);
        }
        #pragma unroll
        for (int off = 32; off >= 1; off >>= 1) lw += __shfl_down(lw, off);
        if (lane == 0) atomicAdd(&wnorm, lw);
    }
    __syncthreads();

    // ---- preload W fragments from staged WT (contiguous b128 reads)
    frag8 wfrag[4][2];
    #pragma unroll
    for (int ks = 0; ks < 4; ++ks)
        #pragma unroll
        for (int c2 = 0; c2 < 2; ++c2) {
            const int e  = wc * 32 + c2 * 16 + l15;
            const int kb = ks * 32 + quad * 8;
            wfrag[ks][c2] = *(const frag8*)&xT[e * BP + kb];
        }
    if (t < NN) {
        adjf[t * AP + t] = 1.0f;
        out_b[t * NN + t] = 1.0f;
    }
    const bool wok = (wnorm <= 1.0f);   // ||W||_2 <= ||W||_F <= 1
    __syncthreads();                    // all wfrag reads done before mm_xw writes xT

    // ---- x0 = relu(xin @ W) -> xT (+ sumsq)
    mm_xw(ybuf, xT, wfrag, wr, wc, l15, quad, &sumsq);
    float ss = sumsq;
    bool skip = (ss == 0.0f) || (wok && ss < EPS);

    // ---- scan i = 1..127
    for (int i = 1; i < NN; ++i) {
        if (skip) {
            const int i0 = i;
            const int nrow = NN - i0;
            for (int v = t; v < nrow * (NN / 4); v += NT) {
                const int r = i0 + (v >> 5), c = (v & 31) * 4;
                float4 zz = {0.f, 0.f, 0.f, 0.f};
                *(float4*)&out_b[r * NN + c] = zz;
            }
            for (int v = t; v < i0 * nrow; v += NT) {
                const int r = v / nrow, c = i0 + v % nrow;
                out_b[r * NN + c] = 0.f;
            }
            __syncthreads();
            if (t >= i0 && t < NN) out_b[t * NN + t] = 1.0f;
            break;
        }

        // --- A: prob partial sums over d (2 d's per thread, b128 j-reads) ---
        {
            const int dg = t >> 4, jv = t & 15, j0 = jv * 8;
            float ac[8] = {0.f, 0.f, 0.f, 0.f, 0.f, 0.f, 0.f, 0.f};
            #pragma unroll
            for (int s = 0; s < 2; ++s) {
                const int d = dg * 2 + s;
                frag8 xj = *(const frag8*)&xT[d * BP + j0];
                const float xi = bf2f(xT[d * BP + i]);
                #pragma unroll
                for (int e2 = 0; e2 < 8; ++e2)
                    ac[e2] = fmaf(xi, bf2f(xj[e2]), ac[e2]);
            }
            float4 p0 = {ac[0], ac[1], ac[2], ac[3]};
            float4 p1 = {ac[4], ac[5], ac[6], ac[7]};
            *(float4*)&scratch[dg * AP + j0]     = p0;
            *(float4*)&scratch[dg * AP + j0 + 4] = p1;
            if (t == NT - 1) sumsq = 0.0f;        // reset for phase F
        }
        __syncthreads();

        // --- B: reduce 64 partials; write raw probs into adjf row/col i + out ---
        {
            const int j = t >> 3, q = t & 7;
            float s = 0.f;
            #pragma unroll
            for (int g = 0; g < 8; ++g) s += scratch[(q * 8 + g) * AP + j];
            s += __shfl_down(s, 4, 8);
            s += __shfl_down(s, 2, 8);
            s += __shfl_down(s, 1, 8);
            if (q == 0 && j < i) {
                adjf[i * AP + j] = s;
                adjf[j * AP + i] = s;
                out_b[i * NN + j] = s;
                out_b[j * NN + i] = s;
            }
        }
        __syncthreads();

        // --- C: degrees -> dinv ---
        {
            const int j = t >> 3, q = t & 7;
            float s = 0.f;
            #pragma unroll
            for (int g = 0; g < 4; ++g) {
                float4 v4 = *(const float4*)&adjf[j * AP + q * 16 + g * 4];
                s += (v4.x + v4.y) + (v4.z + v4.w);
            }
            s += __shfl_down(s, 4, 8);
            s += __shfl_down(s, 2, 8);
            s += __shfl_down(s, 1, 8);
            if (q == 0) dinv[j] = 1.0f / sqrtf(s);
        }
        __syncthreads();

        // --- D: normalize adjf IN PLACE (carried) + bf16 copy (adjn) ---
        {
            const int r = t >> 3, q = t & 7;
            const float dr = dinv[r];
            #pragma unroll
            for (int g = 0; g < 4; ++g) {
                const int c = q * 16 + g * 4;
                float4 v4 = *(const float4*)&adjf[r * AP + c];
                float4 d4 = *(const float4*)&dinv[c];
                v4.x *= dr * d4.x; v4.y *= dr * d4.y;
                v4.z *= dr * d4.z; v4.w *= dr * d4.w;
                *(float4*)&adjf[r * AP + c] = v4;
                short4 p; p.x = bf16c(v4.x); p.y = bf16c(v4.y);
                p.z = bf16c(v4.z); p.w = bf16c(v4.w);
                *(short4*)&ybuf[r * BP + c] = p;
            }
        }
        __syncthreads();

        // --- E: mm1  yT = xT @ adjn (B-frags via adjn symmetry) ---
        {
            const f32x4 z = {0.f, 0.f, 0.f, 0.f};
            f32x4 acc[2][2];
            #pragma unroll
            for (int tr = 0; tr < 2; ++tr) { acc[tr][0] = z; acc[tr][1] = z; }
            #pragma unroll
            for (int ks = 0; ks < 4; ++ks) {
                const int kb = ks * 32 + quad * 8;
                frag8 b0 = *(const frag8*)&ybuf[(wc * 32 + l15) * BP + kb];
                frag8 b1 = *(const frag8*)&ybuf[(wc * 32 + 16 + l15) * BP + kb];
                #pragma unroll
                for (int tr = 0; tr < 2; ++tr) {
                    frag8 a = *(const frag8*)&xT[(wr * 32 + tr * 16 + l15) * BP + kb];
                    acc[tr][0] = __builtin_amdgcn_mfma_f32_16x16x32_bf16(a, b0, acc[tr][0], 0, 0, 0);
                    acc[tr][1] = __builtin_amdgcn_mfma_f32_16x16x32_bf16(a, b1, acc[tr][1], 0, 0, 0);
                }
            }
            __syncthreads();   // adjn reads done before overwriting ybuf with y
            #pragma unroll
            for (int tr = 0; tr < 2; ++tr)
                #pragma unroll
                for (int c2 = 0; c2 < 2; ++c2) {
                    const int n  = wc * 32 + c2 * 16 + l15;      // node (C col)
                    const int d0 = wr * 32 + tr * 16 + quad * 4; // d (C rows)
                    f32x4 v = acc[tr][c2];
                    short4 p; p.x = bf16c(v[0]); p.y = bf16c(v[1]);
                    p.z = bf16c(v[2]); p.w = bf16c(v[3]);
                    *(short4*)&ybuf[n * BP + d0] = p;            // y row-major [node][d]
                }
        }
        __syncthreads();

        // --- F: xT = relu(y @ W)^T + sumsq ---
        mm_xw(ybuf, xT, wfrag, wr, wc, l15, quad, &sumsq);
        ss = sumsq;
        skip = (ss == 0.0f) || (wok && ss < EPS);
    }
}

extern "C" void kernel_launch(void* const* d_in, const int* in_sizes, int n_in,
                              void* d_out, int out_size, void* d_ws, size_t ws_size,
                              hipStream_t stream) {
    const float* x = (const float*)d_in[0];   // (32,128,128) fp32
    const float* W = (const float*)d_in[1];   // (128,128) fp32
    float* out = (float*)d_out;               // (32,128,128) fp32

    const size_t shmem = (size_t)NN * AP * sizeof(float)
                       + (size_t)2 * NN * BP * sizeof(short)
                       + (size_t)NN * sizeof(float);   // 137,728 B
    hipFuncSetAttribute((const void*)gcn_kernel,
                        hipFuncAttributeMaxDynamicSharedMemorySize, (int)shmem);

    gcn_kernel<<<dim3(BATCH), dim3(NT), shmem, stream>>>(x, W, out);
}

// Round 6
// 76.611 us; speedup vs baseline: 1.4126x; 1.4126x over previous
//
#include <hip/hip_runtime.h>
#include <math.h>

// (B, N, D) = (32, 128, 128)
#define BATCH 32
#define NN    128
#define AP    132     // adjf fp32 pitch (floats)
#define BP    136     // bf16 pitch (shorts); rows 272B -> 16B aligned
#define NT    512     // 8 waves (NT=1024 regressed: barrier/critical-path bound)
#define EPS   6e-3f   // truncation: all future |prob| <= ||x||_F^2 < EPS once reached

typedef short frag8 __attribute__((ext_vector_type(8)));   // 8 bf16 = 4 VGPRs
typedef float f32x4 __attribute__((ext_vector_type(4)));   // C/D operand

__device__ __forceinline__ short bf16c(float f) {
    unsigned u = __float_as_uint(f);
    unsigned r = (u + 0x7fffu + ((u >> 16) & 1u)) >> 16;
    return (short)r;
}

// x_new = relu(A @ W): A row-major bf16 [128][BP] (abuf), W-frags in regs.
// Writes x_new into xT (transposed, for E's B-frags) AND back into abuf
// row-major (for P's A/B-frags). Accumulates ||x||_F^2 into *ssp.
__device__ __forceinline__ void mm_xw2(short* __restrict__ abuf,
                                       short* __restrict__ xT,
                                       const frag8 wf[4][2],
                                       int wr, int wc, int l15, int quad,
                                       int lane, float* ssp) {
    const f32x4 z = {0.f, 0.f, 0.f, 0.f};
    f32x4 acc[4][2];
    #pragma unroll
    for (int tr = 0; tr < 4; ++tr) { acc[tr][0] = z; acc[tr][1] = z; }
    #pragma unroll
    for (int ks = 0; ks < 4; ++ks) {
        const int kb = ks * 32 + quad * 8;
        #pragma unroll
        for (int tr = 0; tr < 4; ++tr) {
            frag8 a = *(const frag8*)&abuf[(wr * 64 + tr * 16 + l15) * BP + kb];
            acc[tr][0] = __builtin_amdgcn_mfma_f32_16x16x32_bf16(a, wf[ks][0], acc[tr][0], 0, 0, 0);
            acc[tr][1] = __builtin_amdgcn_mfma_f32_16x16x32_bf16(a, wf[ks][1], acc[tr][1], 0, 0, 0);
        }
    }
    __syncthreads();   // all A-reads of abuf done before overwriting abuf with x_new
    float lss = 0.f;
    #pragma unroll
    for (int tr = 0; tr < 4; ++tr)
        #pragma unroll
        for (int c2 = 0; c2 < 2; ++c2) {
            const int n  = wc * 32 + c2 * 16 + l15;      // out-feature (C col)
            const int m0 = wr * 64 + tr * 16 + quad * 4; // node (C rows, contiguous)
            f32x4 v = acc[tr][c2];
            float r0 = v[0] > 0.f ? v[0] : 0.f;
            float r1 = v[1] > 0.f ? v[1] : 0.f;
            float r2 = v[2] > 0.f ? v[2] : 0.f;
            float r3 = v[3] > 0.f ? v[3] : 0.f;
            lss = fmaf(r0, r0, lss); lss = fmaf(r1, r1, lss);
            lss = fmaf(r2, r2, lss); lss = fmaf(r3, r3, lss);
            short4 p; p.x = bf16c(r0); p.y = bf16c(r1);
            p.z = bf16c(r2); p.w = bf16c(r3);
            *(short4*)&xT[n * BP + m0] = p;              // transposed (feature-major)
            abuf[(m0 + 0) * BP + n] = p.x;               // row-major (node-major)
            abuf[(m0 + 1) * BP + n] = p.y;
            abuf[(m0 + 2) * BP + n] = p.z;
            abuf[(m0 + 3) * BP + n] = p.w;
        }
    #pragma unroll
    for (int off = 32; off >= 1; off >>= 1) lss += __shfl_down(lss, off);
    if (lane == 0) atomicAdd(ssp, lss);
    __syncthreads();
}

__global__ __launch_bounds__(NT, 1)
void gcn_kernel(const float* __restrict__ xin,
                const float* __restrict__ W,
                float* __restrict__ out) {
    extern __shared__ char smem_raw[];
    float* adjf = (float*)smem_raw;               // [128][132] fp32 carried normalized matrix
    short* ybuf = (short*)(adjf + NN * AP);       // [128][136] bf16: xrow / adjn / y (cycled)
    short* xT   = ybuf + NN * BP;                 // [128][136] bf16: WT stage, then x transposed
    float* prob = (float*)(xT + NN * BP);         // [128] masked probs (fp32)
    float* dinv = prob + NN;                      // [128]
    float* rs   = dinv + NN;                      // [128] rowsums of carried normalized matrix
    __shared__ float sumsq;                       // ||x||_F^2
    __shared__ float wnorm;                       // ||W||_F^2
    __shared__ float sprob;                       // sum_{j<i} prob[j]
    __shared__ float aii;                         // adjf[i][i] before step-i writes

    const int t = threadIdx.x;
    const int b = blockIdx.x;
    const int lane = t & 63, w = t >> 6;          // 8 waves
    const int wr = w >> 2, wc = w & 3;            // E/F wave tile: rows 64*wr, cols 32*wc
    const int l15 = lane & 15, quad = lane >> 4;

    const float* xin_b = xin + (size_t)b * NN * NN;
    float*       out_b = out + (size_t)b * NN * NN;

    if (t == 0) { sumsq = 0.0f; wnorm = 0.0f; sprob = 0.0f; }
    __syncthreads();

    // ---- stage: adjf=0, xin->ybuf row-major bf16, W->xT transposed bf16 + wnorm
    for (int e = t; e < NN * AP; e += NT) adjf[e] = 0.0f;
    for (int v = t; v < NN * NN / 4; v += NT) {
        float4 f = ((const float4*)xin_b)[v];
        const int node = v >> 5, c = (v & 31) * 4;
        short4 p; p.x = bf16c(f.x); p.y = bf16c(f.y); p.z = bf16c(f.z); p.w = bf16c(f.w);
        *(short4*)&ybuf[node * BP + c] = p;
    }
    {
        float lw = 0.0f;
        #pragma unroll
        for (int k = 0; k < 8; ++k) {
            const int idx = k * NT + t;           // float4 index into W
            float4 f = ((const float4*)W)[idx];
            lw = fmaf(f.x, f.x, lw); lw = fmaf(f.y, f.y, lw);
            lw = fmaf(f.z, f.z, lw); lw = fmaf(f.w, f.w, lw);
            const int e0 = idx * 4;
            const int d = e0 >> 7, e = e0 & 127;  // W[d][e..e+3]
            xT[(e + 0) * BP + d] = bf16c(f.x);    // WT[e][d]
            xT[(e + 1) * BP + d] = bf16c(f.y);
            xT[(e + 2) * BP + d] = bf16c(f.z);
            xT[(e + 3) * BP + d] = bf16c(f.w);
        }
        #pragma unroll
        for (int off = 32; off >= 1; off >>= 1) lw += __shfl_down(lw, off);
        if (lane == 0) atomicAdd(&wnorm, lw);
    }
    __syncthreads();

    // ---- wfrag: B[k=d][n=e] = W[d][e], read contiguous from staged WT
    frag8 wfrag[4][2];
    #pragma unroll
    for (int ks = 0; ks < 4; ++ks)
        #pragma unroll
        for (int c2 = 0; c2 < 2; ++c2) {
            const int e  = wc * 32 + c2 * 16 + l15;
            const int kb = ks * 32 + quad * 8;
            wfrag[ks][c2] = *(const frag8*)&xT[e * BP + kb];
        }
    if (t < NN) {
        adjf[t * AP + t] = 1.0f;
        out_b[t * NN + t] = 1.0f;
        rs[t] = 1.0f;                       // rowsum of normalized I
    }
    const bool wok = (wnorm <= 1.0f);       // ||W||_2 <= ||W||_F <= 1
    __syncthreads();                        // wfrag reads done before mm_xw2 writes xT

    // ---- x0 = relu(xin @ W) -> xT + xrow(ybuf) + sumsq
    mm_xw2(ybuf, xT, wfrag, wr, wc, l15, quad, lane, &sumsq);
    float ss = sumsq;
    bool skip = (ss == 0.0f) || (wok && ss < EPS);

    // ---- scan i = 1..127
    for (int i = 1; i < NN; ++i) {
        if (skip) {
            const int i0 = i;
            const int nrow = NN - i0;
            for (int v = t; v < nrow * (NN / 4); v += NT) {
                const int r = i0 + (v >> 5), c = (v & 31) * 4;
                float4 zz = {0.f, 0.f, 0.f, 0.f};
                *(float4*)&out_b[r * NN + c] = zz;
            }
            for (int v = t; v < i0 * nrow; v += NT) {
                const int r = v / nrow, c = i0 + v % nrow;
                out_b[r * NN + c] = 0.f;
            }
            __syncthreads();
            if (t >= i0 && t < NN) out_b[t * NN + t] = 1.0f;
            break;
        }

        // --- P: prob via MFMA broadcast. Wave w owns rows w*16..w*16+15.
        //     B cols all equal x_i -> every lane holds prob replicated.
        {
            if (t == 0) aii = adjf[i * AP + i];   // [i][i] untouched by this phase
            const f32x4 z = {0.f, 0.f, 0.f, 0.f};
            f32x4 pa = z, pb = z;
            #pragma unroll
            for (int ks = 0; ks < 4; ++ks) {
                const int kb = ks * 32 + quad * 8;
                frag8 a  = *(const frag8*)&ybuf[(w * 16 + l15) * BP + kb];
                frag8 bb = *(const frag8*)&ybuf[i * BP + kb];   // broadcast read
                if (ks & 1) pb = __builtin_amdgcn_mfma_f32_16x16x32_bf16(a, bb, pb, 0, 0, 0);
                else        pa = __builtin_amdgcn_mfma_f32_16x16x32_bf16(a, bb, pa, 0, 0, 0);
            }
            f32x4 pc = pa + pb;
            float sp = 0.f;
            if (l15 == 0) {                        // lanes 0,16,32,48: 4 probs each
                #pragma unroll
                for (int r = 0; r < 4; ++r) {
                    const int j = w * 16 + quad * 4 + r;
                    const float p = pc[r];
                    const bool m = (j < i);
                    prob[j] = m ? p : 0.f;
                    if (m) {
                        adjf[i * AP + j] = p;  adjf[j * AP + i] = p;
                        out_b[i * NN + j] = p; out_b[j * NN + i] = p;
                        sp += p;
                    }
                }
            }
            sp += __shfl_down(sp, 32);             // lanes 0+=32, 16+=48
            sp += __shfl_down(sp, 16);             // lane 0 += lane 16
            if (lane == 0) atomicAdd(&sprob, sp);
        }
        __syncthreads();

        // --- Q: dinv from incremental degrees (col/row i were 0 off-diag pre-step)
        if (t < NN) {
            const float d = (t == i) ? (aii + sprob) : (rs[t] + prob[t]);
            dinv[t] = 1.0f / sqrtf(d);
        }
        if (t == NN) sumsq = 0.f;                  // reset for this step's F
        __syncthreads();

        // --- D: normalize adjf in place + bf16 cast (adjn->ybuf) + new rowsums
        {
            const int r = t >> 2, q = t & 3;
            const float dr = dinv[r];
            float lrs = 0.f;
            #pragma unroll
            for (int g = 0; g < 8; ++g) {
                const int c = q * 32 + g * 4;
                float4 v4 = *(const float4*)&adjf[r * AP + c];
                float4 d4 = *(const float4*)&dinv[c];
                v4.x *= dr * d4.x; v4.y *= dr * d4.y;
                v4.z *= dr * d4.z; v4.w *= dr * d4.w;
                *(float4*)&adjf[r * AP + c] = v4;
                lrs += (v4.x + v4.y) + (v4.z + v4.w);
                short4 p; p.x = bf16c(v4.x); p.y = bf16c(v4.y);
                p.z = bf16c(v4.z); p.w = bf16c(v4.w);
                *(short4*)&ybuf[r * BP + c] = p;   // adjn (overwrites xrow: P is done)
            }
            lrs += __shfl_down(lrs, 2, 4);
            lrs += __shfl_down(lrs, 1, 4);
            if (q == 0) rs[r] = lrs;
            if (t == NT - 1) sprob = 0.f;          // safe: Q's reads are behind a barrier
        }
        __syncthreads();

        // --- E: y = adjn @ x  (A: adjn rows; B: x cols via xT rows; both b128)
        {
            const f32x4 z = {0.f, 0.f, 0.f, 0.f};
            f32x4 acc[4][2];
            #pragma unroll
            for (int tr = 0; tr < 4; ++tr) { acc[tr][0] = z; acc[tr][1] = z; }
            #pragma unroll
            for (int ks = 0; ks < 4; ++ks) {
                const int kb = ks * 32 + quad * 8;
                frag8 b0 = *(const frag8*)&xT[(wc * 32 + l15) * BP + kb];
                frag8 b1 = *(const frag8*)&xT[(wc * 32 + 16 + l15) * BP + kb];
                #pragma unroll
                for (int tr = 0; tr < 4; ++tr) {
                    frag8 a = *(const frag8*)&ybuf[(wr * 64 + tr * 16 + l15) * BP + kb];
                    acc[tr][0] = __builtin_amdgcn_mfma_f32_16x16x32_bf16(a, b0, acc[tr][0], 0, 0, 0);
                    acc[tr][1] = __builtin_amdgcn_mfma_f32_16x16x32_bf16(a, b1, acc[tr][1], 0, 0, 0);
                }
            }
            __syncthreads();   // adjn reads done before overwriting ybuf with y
            #pragma unroll
            for (int tr = 0; tr < 4; ++tr)
                #pragma unroll
                for (int c2 = 0; c2 < 2; ++c2) {
                    const int n  = wc * 32 + c2 * 16 + l15;      // feature (C col)
                    const int m0 = wr * 64 + tr * 16 + quad * 4; // node (C rows)
                    f32x4 v = acc[tr][c2];
                    ybuf[(m0 + 0) * BP + n] = bf16c(v[0]);       // y row-major [node][d]
                    ybuf[(m0 + 1) * BP + n] = bf16c(v[1]);
                    ybuf[(m0 + 2) * BP + n] = bf16c(v[2]);
                    ybuf[(m0 + 3) * BP + n] = bf16c(v[3]);
                }
        }
        __syncthreads();

        // --- F: x = relu(y @ W) -> xT + xrow(ybuf) + sumsq
        mm_xw2(ybuf, xT, wfrag, wr, wc, l15, quad, lane, &sumsq);
        ss = sumsq;
        skip = (ss == 0.0f) || (wok && ss < EPS);
    }
}

extern "C" void kernel_launch(void* const* d_in, const int* in_sizes, int n_in,
                              void* d_out, int out_size, void* d_ws, size_t ws_size,
                              hipStream_t stream) {
    const float* x = (const float*)d_in[0];   // (32,128,128) fp32
    const float* W = (const float*)d_in[1];   // (128,128) fp32
    float* out = (float*)d_out;               // (32,128,128) fp32

    const size_t shmem = (size_t)NN * AP * sizeof(float)
                       + (size_t)2 * NN * BP * sizeof(short)
                       + (size_t)3 * NN * sizeof(float);   // 138,752 B
    hipFuncSetAttribute((const void*)gcn_kernel,
                        hipFuncAttributeMaxDynamicSharedMemorySize, (int)shmem);

    gcn_kernel<<<dim3(BATCH), dim3(NT), shmem, stream>>>(x, W, out);
}